// Round 4
// baseline (549.893 us; speedup 1.0000x reference)
//
#include <hip/hip_runtime.h>

#define D 64

// ---------------------------------------------------------------------------
// disen_weight = softmax(disen_weight_att, axis=-1) @ relation_emb   [F=4, D=64]
// one block of 64 threads; thread d computes column d for all factors.
// ---------------------------------------------------------------------------
__global__ void disen_kernel(const float* __restrict__ att,   // [F, R]
                             const float* __restrict__ rel,   // [R, D]
                             float* __restrict__ disen,       // [F, D]
                             int nF, int nRel) {
    int d = threadIdx.x;
    if (d >= D) return;
    for (int f = 0; f < nF; ++f) {
        float m = -1e30f;
        for (int r = 0; r < nRel; ++r) m = fmaxf(m, att[f * nRel + r]);
        float sum = 0.0f, w = 0.0f;
        for (int r = 0; r < nRel; ++r) {
            float ex = __expf(att[f * nRel + r] - m);
            sum += ex;
            w   += ex * rel[r * D + d];
        }
        disen[f * D + d] = w / sum;   // (sum_r e_r * rel)/sum == softmax @ rel
    }
}

// ---------------------------------------------------------------------------
// KG aggregate: one wave (64 lanes) per edge; lane = dim.
// eagg[head] += ent[tail] * rel[type];  cnt[head] += 1 (lane 0)
// ---------------------------------------------------------------------------
__global__ void kg_scatter(const float* __restrict__ ent,
                           const float* __restrict__ rel,
                           const int*   __restrict__ eidx,   // [2, E] heads then tails
                           const int*   __restrict__ etype,  // [E]
                           float* __restrict__ eagg,         // [nEnt, D]
                           float* __restrict__ cnt,          // [nEnt]
                           int nE) {
    int gid = blockIdx.x * blockDim.x + threadIdx.x;
    int e = gid >> 6;
    if (e >= nE) return;
    int d = gid & 63;
    int head = eidx[e];        // wave-uniform broadcast loads
    int tail = eidx[nE + e];
    int t    = etype[e];
    float v = ent[tail * D + d] * rel[t * D + d];
    atomicAdd(&eagg[(size_t)head * D + d], v);
    if (d == 0) atomicAdd(&cnt[head], 1.0f);
}

// ---------------------------------------------------------------------------
// COO SpMM: one wave per nnz; uagg[row] += ent[col] * val
// ---------------------------------------------------------------------------
__global__ void spmm_scatter(const float* __restrict__ ent,
                             const float* __restrict__ vals,
                             const int*   __restrict__ rows,
                             const int*   __restrict__ cols,
                             float* __restrict__ uagg,        // [nU, D]
                             int nnz) {
    int gid = blockIdx.x * blockDim.x + threadIdx.x;
    int i = gid >> 6;
    if (i >= nnz) return;
    int d = gid & 63;
    int r = rows[i];
    int c = cols[i];
    float v = ent[c * D + d] * vals[i];
    atomicAdd(&uagg[(size_t)r * D + d], v);
}

// ---------------------------------------------------------------------------
// entity_agg = seg_sum / max(cnt, 1)
// ---------------------------------------------------------------------------
__global__ void ent_norm(float* __restrict__ eagg,
                         const float* __restrict__ cnt,
                         int total) {
    int gid = blockIdx.x * blockDim.x + threadIdx.x;
    if (gid >= total) return;
    float c = cnt[gid >> 6];          // wave-uniform per row
    eagg[gid] /= fmaxf(c, 1.0f);
}

// ---------------------------------------------------------------------------
// user epilogue: one wave per user.
//   s_f = softmax_f( dot(user_emb[u], latent[f]) )       (wave shuffle-reduce)
//   uagg[u,d] = (sum_f s_f * disen[f,d]) * uagg[u,d] + uagg[u,d]
// ---------------------------------------------------------------------------
__global__ void user_final(const float* __restrict__ uemb,   // [nU, D]
                           const float* __restrict__ lat,    // [F, D]
                           const float* __restrict__ disen,  // [F, D]
                           float* __restrict__ uagg,         // [nU, D]
                           int nU) {
    int gid = blockIdx.x * blockDim.x + threadIdx.x;
    int u = gid >> 6;
    if (u >= nU) return;
    int d = gid & 63;

    float e = uemb[(size_t)u * D + d];

    float s[4];
#pragma unroll
    for (int f = 0; f < 4; ++f) {
        float p = e * lat[f * D + d];
#pragma unroll
        for (int off = 32; off > 0; off >>= 1)
            p += __shfl_xor(p, off, 64);
        s[f] = p;                      // full dot, same value in all 64 lanes
    }

    float m = fmaxf(fmaxf(s[0], s[1]), fmaxf(s[2], s[3]));
    float sum = 0.0f;
#pragma unroll
    for (int f = 0; f < 4; ++f) { s[f] = __expf(s[f] - m); sum += s[f]; }
    float inv = 1.0f / sum;

    float w = 0.0f;
#pragma unroll
    for (int f = 0; f < 4; ++f) w += (s[f] * inv) * disen[f * D + d];

    size_t o = (size_t)u * D + d;
    float base = uagg[o];
    uagg[o] = w * base + base;
}

// ---------------------------------------------------------------------------
extern "C" void kernel_launch(void* const* d_in, const int* in_sizes, int n_in,
                              void* d_out, int out_size, void* d_ws, size_t ws_size,
                              hipStream_t stream) {
    const float* ent   = (const float*)d_in[0];   // entity_emb   [nEnt, 64]
    const float* uemb  = (const float*)d_in[1];   // user_emb     [nU, 64]
    const float* lat   = (const float*)d_in[2];   // latent_emb   [F, 64]
    const float* rel   = (const float*)d_in[3];   // relation_emb [R, 64]
    const float* att   = (const float*)d_in[4];   // disen_weight_att [F, R]
    const float* vals  = (const float*)d_in[5];   // interact_vals [nnz]
    const int*   eidx  = (const int*)d_in[6];     // edge_index [2, E]
    const int*   etype = (const int*)d_in[7];     // edge_type [E]
    const int*   irows = (const int*)d_in[8];     // interact_rows [nnz]
    const int*   icols = (const int*)d_in[9];     // interact_cols [nnz]

    int nEnt = in_sizes[0] / D;
    int nU   = in_sizes[1] / D;
    int nF   = in_sizes[2] / D;
    int nRel = in_sizes[3] / D;
    int nnz  = in_sizes[5];
    int nE   = in_sizes[6] / 2;

    float* eagg = (float*)d_out;                       // [nEnt, D]
    float* uagg = (float*)d_out + (size_t)nEnt * D;    // [nU, D]

    // workspace: counts [nEnt] f32, then disen [F, D] f32
    float* cnt = (float*)d_ws;
    size_t cnt_bytes = (((size_t)nEnt * sizeof(float)) + 255) & ~(size_t)255;
    float* disen = (float*)((char*)d_ws + cnt_bytes);

    // zero accumulators every call (harness poisons 0xAA, never re-poisons)
    hipMemsetAsync(d_out, 0, (size_t)out_size * sizeof(float), stream);
    hipMemsetAsync(cnt, 0, (size_t)nEnt * sizeof(float), stream);

    disen_kernel<<<1, 64, 0, stream>>>(att, rel, disen, nF, nRel);

    {
        long long total = (long long)nE * 64;
        int blocks = (int)((total + 255) / 256);
        kg_scatter<<<blocks, 256, 0, stream>>>(ent, rel, eidx, etype, eagg, cnt, nE);
    }
    {
        long long total = (long long)nnz * 64;
        int blocks = (int)((total + 255) / 256);
        spmm_scatter<<<blocks, 256, 0, stream>>>(ent, vals, irows, icols, uagg, nnz);
    }
    {
        int total = nEnt * D;
        ent_norm<<<(total + 255) / 256, 256, 0, stream>>>(eagg, cnt, total);
    }
    {
        long long total = (long long)nU * 64;
        int blocks = (int)((total + 255) / 256);
        user_final<<<blocks, 256, 0, stream>>>(uemb, lat, disen, uagg, nU);
    }
}

// Round 5
// 401.640 us; speedup vs baseline: 1.3691x; 1.3691x over previous
//
#include <hip/hip_runtime.h>

#define D 64

// ===========================================================================
// disen_weight = softmax(disen_weight_att, axis=-1) @ relation_emb   [F, D]
// one block of 64 threads; thread d computes column d for all factors.
// ===========================================================================
__global__ void disen_kernel(const float* __restrict__ att,   // [F, R]
                             const float* __restrict__ rel,   // [R, D]
                             float* __restrict__ disen,       // [F, D]
                             int nF, int nRel) {
    int d = threadIdx.x;
    if (d >= D) return;
    for (int f = 0; f < nF; ++f) {
        float m = -1e30f;
        for (int r = 0; r < nRel; ++r) m = fmaxf(m, att[f * nRel + r]);
        float sum = 0.0f, w = 0.0f;
        for (int r = 0; r < nRel; ++r) {
            float ex = __expf(att[f * nRel + r] - m);
            sum += ex;
            w   += ex * rel[r * D + d];
        }
        disen[f * D + d] = w / sum;
    }
}

// ===========================================================================
// counting-sort machinery: histogram -> exclusive scan (3 kernels) -> fill
// ===========================================================================
__global__ void hist_kernel(const int* __restrict__ keys, int n,
                            int* __restrict__ hist) {
    int i = blockIdx.x * blockDim.x + threadIdx.x;
    if (i < n) atomicAdd(&hist[keys[i]], 1);
}

// per-block exclusive scan of hist -> rowptr[i] (local), block total -> bsum[b]
__global__ void scan_partial(const int* __restrict__ hist, int n,
                             int* __restrict__ rowptr, int* __restrict__ bsum) {
    __shared__ int s[256];
    int t = threadIdx.x;
    int i = blockIdx.x * 256 + t;
    int v = (i < n) ? hist[i] : 0;
    s[t] = v;
    __syncthreads();
    for (int off = 1; off < 256; off <<= 1) {
        int x = (t >= off) ? s[t - off] : 0;
        __syncthreads();
        s[t] += x;
        __syncthreads();
    }
    if (i < n) rowptr[i] = s[t] - v;          // exclusive within block
    if (t == 255) bsum[blockIdx.x] = s[255];  // block total
}

// single-block inclusive scan of block sums (nb <= 1024)
__global__ void scan_bsum(int* __restrict__ bsum, int nb) {
    __shared__ int s[1024];
    int t = threadIdx.x;
    int v = (t < nb) ? bsum[t] : 0;
    s[t] = v;
    __syncthreads();
    for (int off = 1; off < 1024; off <<= 1) {
        int x = (t >= off) ? s[t - off] : 0;
        __syncthreads();
        s[t] += x;
        __syncthreads();
    }
    if (t < nb) bsum[t] = s[t];
}

// add block offsets; also init cursor = rowptr; write rowptr[n] = total
__global__ void scan_finalize(int* __restrict__ rowptr, int n,
                              const int* __restrict__ bsum,
                              int* __restrict__ cursor, int total) {
    int i = blockIdx.x * blockDim.x + threadIdx.x;
    if (i >= n) return;
    int b = i >> 8;
    int rp = rowptr[i] + (b ? bsum[b - 1] : 0);
    rowptr[i] = rp;
    cursor[i] = rp;
    if (i == 0) rowptr[n] = total;
}

// KG edges: bucket by head, pack payload = tail | (type << 20)
__global__ void fill_e(const int* __restrict__ eidx,   // [2, E]
                       const int* __restrict__ etype,  // [E]
                       int nE, int* __restrict__ cursor,
                       int* __restrict__ sorted) {
    int e = blockIdx.x * blockDim.x + threadIdx.x;
    if (e >= nE) return;
    int pos = atomicAdd(&cursor[eidx[e]], 1);
    sorted[pos] = eidx[nE + e] | (etype[e] << 20);
}

// interactions: bucket by user row, carry (col, val)
__global__ void fill_u(const int* __restrict__ rows, const int* __restrict__ cols,
                       const float* __restrict__ vals, int nnz,
                       int* __restrict__ cursor, int* __restrict__ scol,
                       float* __restrict__ sval) {
    int i = blockIdx.x * blockDim.x + threadIdx.x;
    if (i >= nnz) return;
    int pos = atomicAdd(&cursor[rows[i]], 1);
    scol[pos] = cols[i];
    sval[pos] = vals[i];
}

// ===========================================================================
// entity aggregate: wave per entity row; register accumulate; fused mean.
// ===========================================================================
__global__ void agg_e(const float* __restrict__ ent, const float* __restrict__ rel,
                      const int* __restrict__ rowptr, const int* __restrict__ sorted,
                      float* __restrict__ eagg, int nEnt) {
    int gid = blockIdx.x * blockDim.x + threadIdx.x;
    int row = gid >> 6;
    if (row >= nEnt) return;
    int d = gid & 63;
    int beg = rowptr[row], end = rowptr[row + 1];
    float a0 = 0.0f, a1 = 0.0f;
    int k = beg;
    for (; k + 2 <= end; k += 2) {      // 2-wide: 2 gathers in flight
        int p0 = sorted[k], p1 = sorted[k + 1];
        a0 += ent[(size_t)(p0 & 0xFFFFF) * D + d] * rel[(((unsigned)p0) >> 20) * D + d];
        a1 += ent[(size_t)(p1 & 0xFFFFF) * D + d] * rel[(((unsigned)p1) >> 20) * D + d];
    }
    if (k < end) {
        int p0 = sorted[k];
        a0 += ent[(size_t)(p0 & 0xFFFFF) * D + d] * rel[(((unsigned)p0) >> 20) * D + d];
    }
    float c = (float)(end - beg);
    eagg[(size_t)row * D + d] = (a0 + a1) / fmaxf(c, 1.0f);
}

// ===========================================================================
// user aggregate (CSR SpMM) fused with softmax-attention epilogue.
// wave per user; lane = dim. Writes final user_agg directly.
// ===========================================================================
__global__ void agg_u_final(const float* __restrict__ ent,
                            const int* __restrict__ rowptr,
                            const int* __restrict__ scol,
                            const float* __restrict__ sval,
                            const float* __restrict__ uemb,   // [nU, D]
                            const float* __restrict__ lat,    // [4, D]
                            const float* __restrict__ disen,  // [4, D]
                            float* __restrict__ uagg, int nU) {
    int gid = blockIdx.x * blockDim.x + threadIdx.x;
    int u = gid >> 6;
    if (u >= nU) return;
    int d = gid & 63;

    int beg = rowptr[u], end = rowptr[u + 1];
    float a0 = 0.0f, a1 = 0.0f;
    int k = beg;
    for (; k + 2 <= end; k += 2) {
        a0 += ent[(size_t)scol[k] * D + d] * sval[k];
        a1 += ent[(size_t)scol[k + 1] * D + d] * sval[k + 1];
    }
    if (k < end) a0 += ent[(size_t)scol[k] * D + d] * sval[k];
    float agg = a0 + a1;

    // score = softmax_f( dot(uemb[u], lat[f]) )  via full-wave shuffle reduce
    float e = uemb[(size_t)u * D + d];
    float s[4];
#pragma unroll
    for (int f = 0; f < 4; ++f) {
        float p = e * lat[f * D + d];
#pragma unroll
        for (int off = 32; off > 0; off >>= 1) p += __shfl_xor(p, off, 64);
        s[f] = p;
    }
    float m = fmaxf(fmaxf(s[0], s[1]), fmaxf(s[2], s[3]));
    float sum = 0.0f;
#pragma unroll
    for (int f = 0; f < 4; ++f) { s[f] = __expf(s[f] - m); sum += s[f]; }
    float inv = 1.0f / sum;
    float w = 0.0f;
#pragma unroll
    for (int f = 0; f < 4; ++f) w += (s[f] * inv) * disen[f * D + d];

    uagg[(size_t)u * D + d] = w * agg + agg;
}

// ===========================================================================
// Fallback (round-3, proven-correct) atomic-scatter kernels
// ===========================================================================
__global__ void kg_scatter(const float* __restrict__ ent,
                           const float* __restrict__ rel,
                           const int* __restrict__ eidx,
                           const int* __restrict__ etype,
                           float* __restrict__ eagg, float* __restrict__ cnt,
                           int nE) {
    int gid = blockIdx.x * blockDim.x + threadIdx.x;
    int e = gid >> 6;
    if (e >= nE) return;
    int d = gid & 63;
    int head = eidx[e];
    int tail = eidx[nE + e];
    int t = etype[e];
    float v = ent[tail * D + d] * rel[t * D + d];
    atomicAdd(&eagg[(size_t)head * D + d], v);
    if (d == 0) atomicAdd(&cnt[head], 1.0f);
}

__global__ void spmm_scatter(const float* __restrict__ ent,
                             const float* __restrict__ vals,
                             const int* __restrict__ rows,
                             const int* __restrict__ cols,
                             float* __restrict__ uagg, int nnz) {
    int gid = blockIdx.x * blockDim.x + threadIdx.x;
    int i = gid >> 6;
    if (i >= nnz) return;
    int d = gid & 63;
    float v = ent[cols[i] * D + d] * vals[i];
    atomicAdd(&uagg[(size_t)rows[i] * D + d], v);
}

__global__ void ent_norm(float* __restrict__ eagg, const float* __restrict__ cnt,
                         int total) {
    int gid = blockIdx.x * blockDim.x + threadIdx.x;
    if (gid >= total) return;
    float c = cnt[gid >> 6];
    eagg[gid] /= fmaxf(c, 1.0f);
}

__global__ void user_final(const float* __restrict__ uemb,
                           const float* __restrict__ lat,
                           const float* __restrict__ disen,
                           float* __restrict__ uagg, int nU) {
    int gid = blockIdx.x * blockDim.x + threadIdx.x;
    int u = gid >> 6;
    if (u >= nU) return;
    int d = gid & 63;
    float e = uemb[(size_t)u * D + d];
    float s[4];
#pragma unroll
    for (int f = 0; f < 4; ++f) {
        float p = e * lat[f * D + d];
#pragma unroll
        for (int off = 32; off > 0; off >>= 1) p += __shfl_xor(p, off, 64);
        s[f] = p;
    }
    float m = fmaxf(fmaxf(s[0], s[1]), fmaxf(s[2], s[3]));
    float sum = 0.0f;
#pragma unroll
    for (int f = 0; f < 4; ++f) { s[f] = __expf(s[f] - m); sum += s[f]; }
    float inv = 1.0f / sum;
    float w = 0.0f;
#pragma unroll
    for (int f = 0; f < 4; ++f) w += (s[f] * inv) * disen[f * D + d];
    size_t o = (size_t)u * D + d;
    float base = uagg[o];
    uagg[o] = w * base + base;
}

// ===========================================================================
extern "C" void kernel_launch(void* const* d_in, const int* in_sizes, int n_in,
                              void* d_out, int out_size, void* d_ws, size_t ws_size,
                              hipStream_t stream) {
    const float* ent   = (const float*)d_in[0];
    const float* uemb  = (const float*)d_in[1];
    const float* lat   = (const float*)d_in[2];
    const float* rel   = (const float*)d_in[3];
    const float* att   = (const float*)d_in[4];
    const float* vals  = (const float*)d_in[5];
    const int*   eidx  = (const int*)d_in[6];
    const int*   etype = (const int*)d_in[7];
    const int*   irows = (const int*)d_in[8];
    const int*   icols = (const int*)d_in[9];

    int nEnt = in_sizes[0] / D;
    int nU   = in_sizes[1] / D;
    int nF   = in_sizes[2] / D;
    int nRel = in_sizes[3] / D;
    int nnz  = in_sizes[5];
    int nE   = in_sizes[6] / 2;

    float* eagg = (float*)d_out;
    float* uagg = (float*)d_out + (size_t)nEnt * D;

    // ---- workspace carve (256B-aligned regions) ----
    char* base = (char*)d_ws;
    size_t off = 0;
    auto carve = [&](size_t bytes) -> void* {
        void* r = base + off;
        off = (off + bytes + 255) & ~(size_t)255;
        return r;
    };
    float* disen    = (float*)carve((size_t)nF * D * sizeof(float));
    int*   hist_e   = (int*)carve((size_t)nEnt * 4);
    int*   hist_u   = (int*)carve((size_t)nU * 4);
    int*   rowptr_e = (int*)carve((size_t)(nEnt + 1) * 4);
    int*   cursor_e = (int*)carve((size_t)nEnt * 4);
    int*   sorted_e = (int*)carve((size_t)nE * 4);
    int*   rowptr_u = (int*)carve((size_t)(nU + 1) * 4);
    int*   cursor_u = (int*)carve((size_t)nU * 4);
    int*   scol     = (int*)carve((size_t)nnz * 4);
    float* sval     = (float*)carve((size_t)nnz * 4);
    int*   bs_e     = (int*)carve(1024 * 4);
    int*   bs_u     = (int*)carve(1024 * 4);
    size_t need = off;

    int nb_e = (nEnt + 255) / 256;
    int nb_u = (nU + 255) / 256;
    bool fast = (ws_size >= need) && (nF == 4) && (nEnt <= (1 << 20)) &&
                (nRel <= 2048) && (nb_e <= 1024) && (nb_u <= 1024);

    if (fast) {
        hipMemsetAsync(hist_e, 0, (size_t)nEnt * 4, stream);
        hipMemsetAsync(hist_u, 0, (size_t)nU * 4, stream);

        disen_kernel<<<1, 64, 0, stream>>>(att, rel, disen, nF, nRel);

        hist_kernel<<<(nE + 255) / 256, 256, 0, stream>>>(eidx, nE, hist_e);  // heads
        hist_kernel<<<(nnz + 255) / 256, 256, 0, stream>>>(irows, nnz, hist_u);

        scan_partial<<<nb_e, 256, 0, stream>>>(hist_e, nEnt, rowptr_e, bs_e);
        scan_bsum<<<1, 1024, 0, stream>>>(bs_e, nb_e);
        scan_finalize<<<nb_e, 256, 0, stream>>>(rowptr_e, nEnt, bs_e, cursor_e, nE);

        scan_partial<<<nb_u, 256, 0, stream>>>(hist_u, nU, rowptr_u, bs_u);
        scan_bsum<<<1, 1024, 0, stream>>>(bs_u, nb_u);
        scan_finalize<<<nb_u, 256, 0, stream>>>(rowptr_u, nU, bs_u, cursor_u, nnz);

        fill_e<<<(nE + 255) / 256, 256, 0, stream>>>(eidx, etype, nE, cursor_e, sorted_e);
        fill_u<<<(nnz + 255) / 256, 256, 0, stream>>>(irows, icols, vals, nnz,
                                                      cursor_u, scol, sval);

        {
            long long tot = (long long)nEnt * 64;
            agg_e<<<(int)((tot + 255) / 256), 256, 0, stream>>>(ent, rel, rowptr_e,
                                                                sorted_e, eagg, nEnt);
        }
        {
            long long tot = (long long)nU * 64;
            agg_u_final<<<(int)((tot + 255) / 256), 256, 0, stream>>>(
                ent, rowptr_u, scol, sval, uemb, lat, disen, uagg, nU);
        }
    } else {
        // ---- round-3 proven path ----
        float* cnt = (float*)d_ws;
        size_t cnt_bytes = (((size_t)nEnt * sizeof(float)) + 255) & ~(size_t)255;
        float* disen_fb = (float*)((char*)d_ws + cnt_bytes);

        hipMemsetAsync(d_out, 0, (size_t)out_size * sizeof(float), stream);
        hipMemsetAsync(cnt, 0, (size_t)nEnt * sizeof(float), stream);

        disen_kernel<<<1, 64, 0, stream>>>(att, rel, disen_fb, nF, nRel);
        {
            long long total = (long long)nE * 64;
            kg_scatter<<<(int)((total + 255) / 256), 256, 0, stream>>>(
                ent, rel, eidx, etype, eagg, cnt, nE);
        }
        {
            long long total = (long long)nnz * 64;
            spmm_scatter<<<(int)((total + 255) / 256), 256, 0, stream>>>(
                ent, vals, irows, icols, uagg, nnz);
        }
        {
            int total = nEnt * D;
            ent_norm<<<(total + 255) / 256, 256, 0, stream>>>(eagg, cnt, total);
        }
        {
            long long total = (long long)nU * 64;
            user_final<<<(int)((total + 255) / 256), 256, 0, stream>>>(
                uemb, lat, disen_fb, uagg, nU);
        }
    }
}

// Round 7
// 335.893 us; speedup vs baseline: 1.6371x; 1.1957x over previous
//
#include <hip/hip_runtime.h>

#define D 64

// ===========================================================================
// disen_weight = softmax(disen_weight_att, axis=-1) @ relation_emb   [F, D]
// ===========================================================================
__global__ void disen_kernel(const float* __restrict__ att,   // [F, R]
                             const float* __restrict__ rel,   // [R, D]
                             float* __restrict__ disen,       // [F, D]
                             int nF, int nRel) {
    int d = threadIdx.x;
    if (d >= D) return;
    for (int f = 0; f < nF; ++f) {
        float m = -1e30f;
        for (int r = 0; r < nRel; ++r) m = fmaxf(m, att[f * nRel + r]);
        float sum = 0.0f, w = 0.0f;
        for (int r = 0; r < nRel; ++r) {
            float ex = __expf(att[f * nRel + r] - m);
            sum += ex;
            w   += ex * rel[r * D + d];
        }
        disen[f * D + d] = w / sum;
    }
}

// ===========================================================================
// TIER 1: fixed-capacity per-row bins (no histogram, no scan).
// One fused scatter pass: KG edges -> bins_e[head], interactions -> bins_u[row].
// Overflow (rare) falls back to direct f32 atomics into the pre-zeroed output.
// ===========================================================================
__device__ __forceinline__ void do_kg(int i, const int* __restrict__ eidx,
                                      const int* __restrict__ etype, int nE,
                                      const float* __restrict__ ent,
                                      const float* __restrict__ rel,
                                      int* __restrict__ cnt_e,
                                      int* __restrict__ bins_e, int cap_e,
                                      float* __restrict__ eagg) {
    if (i >= nE) return;
    int head = eidx[i];
    int tail = eidx[nE + i];
    int t    = etype[i];
    int pos  = atomicAdd(&cnt_e[head], 1);
    if (pos < cap_e) {
        bins_e[(size_t)head * cap_e + pos] = tail | (t << 20);
    } else {                                   // rare overflow: direct atomic
        for (int d = 0; d < D; ++d)
            atomicAdd(&eagg[(size_t)head * D + d],
                      ent[(size_t)tail * D + d] * rel[t * D + d]);
    }
}

__device__ __forceinline__ void do_usr(int i, const int* __restrict__ rows,
                                       const int* __restrict__ cols,
                                       const float* __restrict__ vals, int nnz,
                                       const float* __restrict__ ent,
                                       int* __restrict__ cnt_u,
                                       int2* __restrict__ bins_u, int cap_u,
                                       float* __restrict__ uagg) {
    if (i >= nnz) return;
    int r = rows[i];
    int c = cols[i];
    float v = vals[i];
    int pos = atomicAdd(&cnt_u[r], 1);
    if (pos < cap_u) {
        bins_u[(size_t)r * cap_u + pos] = make_int2(c, __float_as_int(v));
    } else {
        for (int d = 0; d < D; ++d)
            atomicAdd(&uagg[(size_t)r * D + d], ent[(size_t)c * D + d] * v);
    }
}

// fused scatter: each thread drives up to 4 independent latency chains.
// FIX (R6 bug): hard-bound threads at `half` — the grid's ceil-to-256 padding
// otherwise makes threads [half, gridSize) alias indices already covered by
// threads [0,224) via i+half, double-counting ~224 edges+interactions.
__global__ void fill_both(const int* __restrict__ eidx, const int* __restrict__ etype,
                          int nE, const float* __restrict__ ent,
                          const float* __restrict__ rel,
                          int* __restrict__ cnt_e, int* __restrict__ bins_e,
                          int cap_e, float* __restrict__ eagg,
                          const int* __restrict__ irows, const int* __restrict__ icols,
                          const float* __restrict__ vals, int nnz,
                          int* __restrict__ cnt_u, int2* __restrict__ bins_u,
                          int cap_u, float* __restrict__ uagg, int half) {
    int i = blockIdx.x * blockDim.x + threadIdx.x;
    if (i >= half) return;                    // <-- the fix
    do_kg (i,        eidx, etype, nE, ent, rel, cnt_e, bins_e, cap_e, eagg);
    do_usr(i,        irows, icols, vals, nnz, ent, cnt_u, bins_u, cap_u, uagg);
    do_kg (i + half, eidx, etype, nE, ent, rel, cnt_e, bins_e, cap_e, eagg);
    do_usr(i + half, irows, icols, vals, nnz, ent, cnt_u, bins_u, cap_u, uagg);
}

// entity aggregate from bins: wave per row, lane = dim, fused mean.
__global__ void agg_e_bins(const float* __restrict__ ent, const float* __restrict__ rel,
                           const int* __restrict__ cnt_e, const int* __restrict__ bins_e,
                           int cap_e, float* __restrict__ eagg, int nEnt) {
    int gid = blockIdx.x * blockDim.x + threadIdx.x;
    int row = gid >> 6;
    if (row >= nEnt) return;
    int d = gid & 63;
    int c = cnt_e[row];
    int n = min(c, cap_e);
    const int* b = bins_e + (size_t)row * cap_e;
    float a0 = 0.0f, a1 = 0.0f;
    int k = 0;
    for (; k + 2 <= n; k += 2) {
        int p0 = b[k], p1 = b[k + 1];
        a0 += ent[(size_t)(p0 & 0xFFFFF) * D + d] * rel[(((unsigned)p0) >> 20) * D + d];
        a1 += ent[(size_t)(p1 & 0xFFFFF) * D + d] * rel[(((unsigned)p1) >> 20) * D + d];
    }
    if (k < n) {
        int p0 = b[k];
        a0 += ent[(size_t)(p0 & 0xFFFFF) * D + d] * rel[(((unsigned)p0) >> 20) * D + d];
    }
    float base = (c > cap_e) ? eagg[(size_t)row * D + d] : 0.0f;  // overflow part
    eagg[(size_t)row * D + d] = (base + a0 + a1) / fmaxf((float)c, 1.0f);
}

// user aggregate from bins fused with softmax-attention epilogue.
__global__ void agg_u_bins(const float* __restrict__ ent,
                           const int* __restrict__ cnt_u, const int2* __restrict__ bins_u,
                           int cap_u, const float* __restrict__ uemb,
                           const float* __restrict__ lat, const float* __restrict__ disen,
                           float* __restrict__ uagg, int nU) {
    int gid = blockIdx.x * blockDim.x + threadIdx.x;
    int u = gid >> 6;
    if (u >= nU) return;
    int d = gid & 63;
    int c = cnt_u[u];
    int n = min(c, cap_u);
    const int2* b = bins_u + (size_t)u * cap_u;
    float a0 = 0.0f, a1 = 0.0f;
    int k = 0;
    for (; k + 2 <= n; k += 2) {
        int2 p0 = b[k], p1 = b[k + 1];
        a0 += ent[(size_t)p0.x * D + d] * __int_as_float(p0.y);
        a1 += ent[(size_t)p1.x * D + d] * __int_as_float(p1.y);
    }
    if (k < n) {
        int2 p0 = b[k];
        a0 += ent[(size_t)p0.x * D + d] * __int_as_float(p0.y);
    }
    float base = (c > cap_u) ? uagg[(size_t)u * D + d] : 0.0f;
    float agg = base + a0 + a1;

    // score = softmax_f( dot(uemb[u], lat[f]) ) via full-wave shuffle reduce
    float e = uemb[(size_t)u * D + d];
    float s[4];
#pragma unroll
    for (int f = 0; f < 4; ++f) {
        float p = e * lat[f * D + d];
#pragma unroll
        for (int off = 32; off > 0; off >>= 1) p += __shfl_xor(p, off, 64);
        s[f] = p;
    }
    float m = fmaxf(fmaxf(s[0], s[1]), fmaxf(s[2], s[3]));
    float sum = 0.0f;
#pragma unroll
    for (int f = 0; f < 4; ++f) { s[f] = __expf(s[f] - m); sum += s[f]; }
    float inv = 1.0f / sum;
    float w = 0.0f;
#pragma unroll
    for (int f = 0; f < 4; ++f) w += (s[f] * inv) * disen[f * D + d];

    uagg[(size_t)u * D + d] = w * agg + agg;
}

// ===========================================================================
// TIER 2: counting-sort -> CSR (round-5 proven path)
// ===========================================================================
__global__ void hist_kernel(const int* __restrict__ keys, int n,
                            int* __restrict__ hist) {
    int i = blockIdx.x * blockDim.x + threadIdx.x;
    if (i < n) atomicAdd(&hist[keys[i]], 1);
}

__global__ void scan_partial(const int* __restrict__ hist, int n,
                             int* __restrict__ rowptr, int* __restrict__ bsum) {
    __shared__ int s[256];
    int t = threadIdx.x;
    int i = blockIdx.x * 256 + t;
    int v = (i < n) ? hist[i] : 0;
    s[t] = v;
    __syncthreads();
    for (int off = 1; off < 256; off <<= 1) {
        int x = (t >= off) ? s[t - off] : 0;
        __syncthreads();
        s[t] += x;
        __syncthreads();
    }
    if (i < n) rowptr[i] = s[t] - v;
    if (t == 255) bsum[blockIdx.x] = s[255];
}

__global__ void scan_bsum(int* __restrict__ bsum, int nb) {
    __shared__ int s[1024];
    int t = threadIdx.x;
    int v = (t < nb) ? bsum[t] : 0;
    s[t] = v;
    __syncthreads();
    for (int off = 1; off < 1024; off <<= 1) {
        int x = (t >= off) ? s[t - off] : 0;
        __syncthreads();
        s[t] += x;
        __syncthreads();
    }
    if (t < nb) bsum[t] = s[t];
}

__global__ void scan_finalize(int* __restrict__ rowptr, int n,
                              const int* __restrict__ bsum,
                              int* __restrict__ cursor, int total) {
    int i = blockIdx.x * blockDim.x + threadIdx.x;
    if (i >= n) return;
    int b = i >> 8;
    int rp = rowptr[i] + (b ? bsum[b - 1] : 0);
    rowptr[i] = rp;
    cursor[i] = rp;
    if (i == 0) rowptr[n] = total;
}

__global__ void fill_e(const int* __restrict__ eidx, const int* __restrict__ etype,
                       int nE, int* __restrict__ cursor, int* __restrict__ sorted) {
    int e = blockIdx.x * blockDim.x + threadIdx.x;
    if (e >= nE) return;
    int pos = atomicAdd(&cursor[eidx[e]], 1);
    sorted[pos] = eidx[nE + e] | (etype[e] << 20);
}

__global__ void fill_u(const int* __restrict__ rows, const int* __restrict__ cols,
                       const float* __restrict__ vals, int nnz,
                       int* __restrict__ cursor, int* __restrict__ scol,
                       float* __restrict__ sval) {
    int i = blockIdx.x * blockDim.x + threadIdx.x;
    if (i >= nnz) return;
    int pos = atomicAdd(&cursor[rows[i]], 1);
    scol[pos] = cols[i];
    sval[pos] = vals[i];
}

__global__ void agg_e(const float* __restrict__ ent, const float* __restrict__ rel,
                      const int* __restrict__ rowptr, const int* __restrict__ sorted,
                      float* __restrict__ eagg, int nEnt) {
    int gid = blockIdx.x * blockDim.x + threadIdx.x;
    int row = gid >> 6;
    if (row >= nEnt) return;
    int d = gid & 63;
    int beg = rowptr[row], end = rowptr[row + 1];
    float a0 = 0.0f, a1 = 0.0f;
    int k = beg;
    for (; k + 2 <= end; k += 2) {
        int p0 = sorted[k], p1 = sorted[k + 1];
        a0 += ent[(size_t)(p0 & 0xFFFFF) * D + d] * rel[(((unsigned)p0) >> 20) * D + d];
        a1 += ent[(size_t)(p1 & 0xFFFFF) * D + d] * rel[(((unsigned)p1) >> 20) * D + d];
    }
    if (k < end) {
        int p0 = sorted[k];
        a0 += ent[(size_t)(p0 & 0xFFFFF) * D + d] * rel[(((unsigned)p0) >> 20) * D + d];
    }
    float c = (float)(end - beg);
    eagg[(size_t)row * D + d] = (a0 + a1) / fmaxf(c, 1.0f);
}

__global__ void agg_u_final(const float* __restrict__ ent,
                            const int* __restrict__ rowptr,
                            const int* __restrict__ scol,
                            const float* __restrict__ sval,
                            const float* __restrict__ uemb,
                            const float* __restrict__ lat,
                            const float* __restrict__ disen,
                            float* __restrict__ uagg, int nU) {
    int gid = blockIdx.x * blockDim.x + threadIdx.x;
    int u = gid >> 6;
    if (u >= nU) return;
    int d = gid & 63;
    int beg = rowptr[u], end = rowptr[u + 1];
    float a0 = 0.0f, a1 = 0.0f;
    int k = beg;
    for (; k + 2 <= end; k += 2) {
        a0 += ent[(size_t)scol[k] * D + d] * sval[k];
        a1 += ent[(size_t)scol[k + 1] * D + d] * sval[k + 1];
    }
    if (k < end) a0 += ent[(size_t)scol[k] * D + d] * sval[k];
    float agg = a0 + a1;

    float e = uemb[(size_t)u * D + d];
    float s[4];
#pragma unroll
    for (int f = 0; f < 4; ++f) {
        float p = e * lat[f * D + d];
#pragma unroll
        for (int off = 32; off > 0; off >>= 1) p += __shfl_xor(p, off, 64);
        s[f] = p;
    }
    float m = fmaxf(fmaxf(s[0], s[1]), fmaxf(s[2], s[3]));
    float sum = 0.0f;
#pragma unroll
    for (int f = 0; f < 4; ++f) { s[f] = __expf(s[f] - m); sum += s[f]; }
    float inv = 1.0f / sum;
    float w = 0.0f;
#pragma unroll
    for (int f = 0; f < 4; ++f) w += (s[f] * inv) * disen[f * D + d];

    uagg[(size_t)u * D + d] = w * agg + agg;
}

// ===========================================================================
// TIER 3: direct atomic scatter (round-3 proven path)
// ===========================================================================
__global__ void kg_scatter(const float* __restrict__ ent, const float* __restrict__ rel,
                           const int* __restrict__ eidx, const int* __restrict__ etype,
                           float* __restrict__ eagg, float* __restrict__ cnt, int nE) {
    int gid = blockIdx.x * blockDim.x + threadIdx.x;
    int e = gid >> 6;
    if (e >= nE) return;
    int d = gid & 63;
    int head = eidx[e];
    int tail = eidx[nE + e];
    int t = etype[e];
    float v = ent[tail * D + d] * rel[t * D + d];
    atomicAdd(&eagg[(size_t)head * D + d], v);
    if (d == 0) atomicAdd(&cnt[head], 1.0f);
}

__global__ void spmm_scatter(const float* __restrict__ ent, const float* __restrict__ vals,
                             const int* __restrict__ rows, const int* __restrict__ cols,
                             float* __restrict__ uagg, int nnz) {
    int gid = blockIdx.x * blockDim.x + threadIdx.x;
    int i = gid >> 6;
    if (i >= nnz) return;
    int d = gid & 63;
    float v = ent[cols[i] * D + d] * vals[i];
    atomicAdd(&uagg[(size_t)rows[i] * D + d], v);
}

__global__ void ent_norm(float* __restrict__ eagg, const float* __restrict__ cnt,
                         int total) {
    int gid = blockIdx.x * blockDim.x + threadIdx.x;
    if (gid >= total) return;
    float c = cnt[gid >> 6];
    eagg[gid] /= fmaxf(c, 1.0f);
}

__global__ void user_final(const float* __restrict__ uemb, const float* __restrict__ lat,
                           const float* __restrict__ disen, float* __restrict__ uagg,
                           int nU) {
    int gid = blockIdx.x * blockDim.x + threadIdx.x;
    int u = gid >> 6;
    if (u >= nU) return;
    int d = gid & 63;
    float e = uemb[(size_t)u * D + d];
    float s[4];
#pragma unroll
    for (int f = 0; f < 4; ++f) {
        float p = e * lat[f * D + d];
#pragma unroll
        for (int off = 32; off > 0; off >>= 1) p += __shfl_xor(p, off, 64);
        s[f] = p;
    }
    float m = fmaxf(fmaxf(s[0], s[1]), fmaxf(s[2], s[3]));
    float sum = 0.0f;
#pragma unroll
    for (int f = 0; f < 4; ++f) { s[f] = __expf(s[f] - m); sum += s[f]; }
    float inv = 1.0f / sum;
    float w = 0.0f;
#pragma unroll
    for (int f = 0; f < 4; ++f) w += (s[f] * inv) * disen[f * D + d];
    size_t o = (size_t)u * D + d;
    float base = uagg[o];
    uagg[o] = w * base + base;
}

// ===========================================================================
extern "C" void kernel_launch(void* const* d_in, const int* in_sizes, int n_in,
                              void* d_out, int out_size, void* d_ws, size_t ws_size,
                              hipStream_t stream) {
    const float* ent   = (const float*)d_in[0];
    const float* uemb  = (const float*)d_in[1];
    const float* lat   = (const float*)d_in[2];
    const float* rel   = (const float*)d_in[3];
    const float* att   = (const float*)d_in[4];
    const float* vals  = (const float*)d_in[5];
    const int*   eidx  = (const int*)d_in[6];
    const int*   etype = (const int*)d_in[7];
    const int*   irows = (const int*)d_in[8];
    const int*   icols = (const int*)d_in[9];

    int nEnt = in_sizes[0] / D;
    int nU   = in_sizes[1] / D;
    int nF   = in_sizes[2] / D;
    int nRel = in_sizes[3] / D;
    int nnz  = in_sizes[5];
    int nE   = in_sizes[6] / 2;

    float* eagg = (float*)d_out;
    float* uagg = (float*)d_out + (size_t)nEnt * D;

    bool shapes_ok = (nF == 4) && (nEnt <= (1 << 20)) && (nRel <= 2048);

    // ---------------- tier-1: per-row bins ----------------
    const int cap_opts[3][2] = {{64, 64}, {32, 48}, {24, 40}};
    int cap_e = 0, cap_u = 0;
    float* disen1 = nullptr; int* cnt_e = nullptr; int* cnt_u = nullptr;
    int* bins_e = nullptr; int2* bins_u = nullptr;
    for (int o = 0; o < 3 && shapes_ok; ++o) {
        int ce = cap_opts[o][0], cu = cap_opts[o][1];
        char* base = (char*)d_ws;
        size_t off = 0;
        auto carve = [&](size_t bytes) -> void* {
            void* r = base + off;
            off = (off + bytes + 255) & ~(size_t)255;
            return r;
        };
        float* _disen = (float*)carve((size_t)nF * D * 4);
        int* _ce = (int*)carve((size_t)nEnt * 4);
        int* _cu = (int*)carve((size_t)nU * 4);
        int* _be = (int*)carve((size_t)nEnt * ce * 4);
        int2* _bu = (int2*)carve((size_t)nU * cu * 8);
        if (off <= ws_size) {
            cap_e = ce; cap_u = cu;
            disen1 = _disen; cnt_e = _ce; cnt_u = _cu; bins_e = _be; bins_u = _bu;
            break;
        }
    }

    if (cap_e > 0) {
        hipMemsetAsync(d_out, 0, (size_t)out_size * sizeof(float), stream);   // overflow base
        hipMemsetAsync(cnt_e, 0, (size_t)nEnt * 4, stream);
        hipMemsetAsync(cnt_u, 0, (size_t)nU * 4, stream);

        disen_kernel<<<1, 64, 0, stream>>>(att, rel, disen1, nF, nRel);

        int mx = (nE > nnz) ? nE : nnz;
        int half = (mx + 1) / 2;
        fill_both<<<(half + 255) / 256, 256, 0, stream>>>(
            eidx, etype, nE, ent, rel, cnt_e, bins_e, cap_e, eagg,
            irows, icols, vals, nnz, cnt_u, bins_u, cap_u, uagg, half);

        {
            long long tot = (long long)nEnt * 64;
            agg_e_bins<<<(int)((tot + 255) / 256), 256, 0, stream>>>(
                ent, rel, cnt_e, bins_e, cap_e, eagg, nEnt);
        }
        {
            long long tot = (long long)nU * 64;
            agg_u_bins<<<(int)((tot + 255) / 256), 256, 0, stream>>>(
                ent, cnt_u, bins_u, cap_u, uemb, lat, disen1, uagg, nU);
        }
        return;
    }

    // ---------------- tier-2: counting-sort CSR (round-5) ----------------
    {
        char* base = (char*)d_ws;
        size_t off = 0;
        auto carve = [&](size_t bytes) -> void* {
            void* r = base + off;
            off = (off + bytes + 255) & ~(size_t)255;
            return r;
        };
        float* disen2   = (float*)carve((size_t)nF * D * 4);
        int*   hist_e   = (int*)carve((size_t)nEnt * 4);
        int*   hist_u   = (int*)carve((size_t)nU * 4);
        int*   rowptr_e = (int*)carve((size_t)(nEnt + 1) * 4);
        int*   cursor_e = (int*)carve((size_t)nEnt * 4);
        int*   sorted_e = (int*)carve((size_t)nE * 4);
        int*   rowptr_u = (int*)carve((size_t)(nU + 1) * 4);
        int*   cursor_u = (int*)carve((size_t)nU * 4);
        int*   scol     = (int*)carve((size_t)nnz * 4);
        float* sval     = (float*)carve((size_t)nnz * 4);
        int*   bs_e     = (int*)carve(1024 * 4);
        int*   bs_u     = (int*)carve(1024 * 4);
        size_t need = off;

        int nb_e = (nEnt + 255) / 256;
        int nb_u = (nU + 255) / 256;
        bool fast = (ws_size >= need) && shapes_ok && (nb_e <= 1024) && (nb_u <= 1024);

        if (fast) {
            hipMemsetAsync(hist_e, 0, (size_t)nEnt * 4, stream);
            hipMemsetAsync(hist_u, 0, (size_t)nU * 4, stream);

            disen_kernel<<<1, 64, 0, stream>>>(att, rel, disen2, nF, nRel);

            hist_kernel<<<(nE + 255) / 256, 256, 0, stream>>>(eidx, nE, hist_e);
            hist_kernel<<<(nnz + 255) / 256, 256, 0, stream>>>(irows, nnz, hist_u);

            scan_partial<<<nb_e, 256, 0, stream>>>(hist_e, nEnt, rowptr_e, bs_e);
            scan_bsum<<<1, 1024, 0, stream>>>(bs_e, nb_e);
            scan_finalize<<<nb_e, 256, 0, stream>>>(rowptr_e, nEnt, bs_e, cursor_e, nE);

            scan_partial<<<nb_u, 256, 0, stream>>>(hist_u, nU, rowptr_u, bs_u);
            scan_bsum<<<1, 1024, 0, stream>>>(bs_u, nb_u);
            scan_finalize<<<nb_u, 256, 0, stream>>>(rowptr_u, nU, bs_u, cursor_u, nnz);

            fill_e<<<(nE + 255) / 256, 256, 0, stream>>>(eidx, etype, nE, cursor_e, sorted_e);
            fill_u<<<(nnz + 255) / 256, 256, 0, stream>>>(irows, icols, vals, nnz,
                                                          cursor_u, scol, sval);
            {
                long long tot = (long long)nEnt * 64;
                agg_e<<<(int)((tot + 255) / 256), 256, 0, stream>>>(ent, rel, rowptr_e,
                                                                    sorted_e, eagg, nEnt);
            }
            {
                long long tot = (long long)nU * 64;
                agg_u_final<<<(int)((tot + 255) / 256), 256, 0, stream>>>(
                    ent, rowptr_u, scol, sval, uemb, lat, disen2, uagg, nU);
            }
            return;
        }
    }

    // ---------------- tier-3: direct atomics (round-3) ----------------
    {
        float* cnt = (float*)d_ws;
        size_t cnt_bytes = (((size_t)nEnt * sizeof(float)) + 255) & ~(size_t)255;
        float* disen3 = (float*)((char*)d_ws + cnt_bytes);

        hipMemsetAsync(d_out, 0, (size_t)out_size * sizeof(float), stream);
        hipMemsetAsync(cnt, 0, (size_t)nEnt * sizeof(float), stream);

        disen_kernel<<<1, 64, 0, stream>>>(att, rel, disen3, nF, nRel);
        {
            long long total = (long long)nE * 64;
            kg_scatter<<<(int)((total + 255) / 256), 256, 0, stream>>>(
                ent, rel, eidx, etype, eagg, cnt, nE);
        }
        {
            long long total = (long long)nnz * 64;
            spmm_scatter<<<(int)((total + 255) / 256), 256, 0, stream>>>(
                ent, vals, irows, icols, uagg, nnz);
        }
        {
            int total = nEnt * D;
            ent_norm<<<(total + 255) / 256, 256, 0, stream>>>(eagg, cnt, total);
        }
        {
            long long total = (long long)nU * 64;
            user_final<<<(int)((total + 255) / 256), 256, 0, stream>>>(
                uemb, lat, disen3, uagg, nU);
        }
    }
}